// Round 3
// baseline (2314.788 us; speedup 1.0000x reference)
//
#include <hip/hip_runtime.h>

// K-means (8 clusters, 10 iters) on 64 batches of 512*512 RGB pixels,
// bit-exact jax.random init (partitionable threefry, xor-fold bits,
// 2-round stable-sort permutation). Verified passing in round 2.
//
// Round-3 changes (perf only, init indices must stay identical):
//  - bits1 stored to d_ws (if ws_size permits) so histogram + bin-capture
//    passes READ instead of recomputing threefry (~2x init cost removed).
//  - kmeans_update fused into kmeans_assign via per-batch atomic ticket
//    (removes 10 single-block serializing dispatches).
//  - threefry rotl via v_alignbit builtin; packed-u32 argmin in assign;
//    parallel prefix + wave-min extraction in k2.

#define NBATCH 64
#define NPIX   262144   // 512*512 = 2^18
#define NCLUST 8
#define NITER  10
#define NBIN   1024
#define CAP2   1024     // round-2 candidates: E=512, +22 sigma
#define CAP1   512      // per-bin round-1 candidates: E=256, +16 sigma
#define THRESH2 (1u << 23)
#define IDXMASK 0x3FFFFull

struct WS {
  unsigned long long list2[NBATCH][CAP2];            // (bits2<<18)|pos
  unsigned long long list1[NBATCH][NCLUST][CAP1];    // (bits1<<18)|i
  unsigned int subkeys[NBATCH][4];                   // s1k0,s1k1,s2k0,s2k1
  unsigned int hist[NBATCH][NBIN];
  unsigned int cnt2[NBATCH];
  unsigned int cnt1[NBATCH][NCLUST];
  unsigned int binr[NBATCH][NCLUST][2];              // bin, intra-bin rank
  float cent[NITER + 1][NBATCH][NCLUST][3];          // per-iteration centroids
  float sums[NITER][NBATCH][NCLUST][4];              // per-iteration accumulators
  unsigned int done[NITER][NBATCH];                  // per-iteration tickets
  unsigned int bits1[NBATCH][NPIX];                  // big-path only (64 MB)
};

__device__ __forceinline__ unsigned int rotl32(unsigned int x, int d) {
  // rotl(x,d) == funnel-shift-right(x,x,32-d) == v_alignbit_b32
  return __builtin_amdgcn_alignbit(x, x, (unsigned int)(32 - d));
}

__device__ __forceinline__ void threefry2x32(unsigned int k0, unsigned int k1,
                                             unsigned int x0, unsigned int x1,
                                             unsigned int &y0, unsigned int &y1) {
  const unsigned int ks2 = k0 ^ k1 ^ 0x1BD11BDAu;
  x0 += k0; x1 += k1;
#define TF_ROUND(r) { x0 += x1; x1 = rotl32(x1, r); x1 ^= x0; }
  TF_ROUND(13) TF_ROUND(15) TF_ROUND(26) TF_ROUND(6)
  x0 += k1;  x1 += ks2 + 1u;
  TF_ROUND(17) TF_ROUND(29) TF_ROUND(16) TF_ROUND(24)
  x0 += ks2; x1 += k0 + 2u;
  TF_ROUND(13) TF_ROUND(15) TF_ROUND(26) TF_ROUND(6)
  x0 += k0;  x1 += k1 + 3u;
  TF_ROUND(17) TF_ROUND(29) TF_ROUND(16) TF_ROUND(24)
  x0 += k1;  x1 += ks2 + 4u;
  TF_ROUND(13) TF_ROUND(15) TF_ROUND(26) TF_ROUND(6)
  x0 += ks2; x1 += k0 + 5u;
#undef TF_ROUND
  y0 = x0; y1 = x1;
}

__device__ __forceinline__ unsigned int rb32(unsigned int k0, unsigned int k1,
                                             unsigned int i) {
  unsigned int y0, y1;
  threefry2x32(k0, k1, 0u, i, y0, y1);
  return y0 ^ y1;
}

__device__ __forceinline__ unsigned long long umin64(unsigned long long a,
                                                     unsigned long long b) {
  return a < b ? a : b;
}

// ---------------------------------------------------------------- K0: setup
__global__ __launch_bounds__(256) void k0_setup(const float* __restrict__ in,
                                                WS* __restrict__ ws) {
  const int b = blockIdx.x, t = threadIdx.x;
  for (int i = t; i < NBIN; i += 256) ws->hist[b][i] = 0u;
  for (int i = t; i < NITER * NCLUST * 4; i += 256)
    ws->sums[i >> 5][b][(i >> 2) & 7][i & 3] = 0.f;
  if (t < NITER) ws->done[t][b] = 0u;
  if (t < NCLUST) {
    ws->cnt1[b][t] = 0u;
    const float* p = in + ((size_t)b * NPIX + (size_t)t) * 3;  // fallback init
    ws->cent[0][b][t][0] = p[0];
    ws->cent[0][b][t][1] = p[1];
    ws->cent[0][b][t][2] = p[2];
  }
  if (t == 0) {
    ws->cnt2[b] = 0u;
    unsigned int kb0, kb1, ka0, ka1, u0, u1;
    threefry2x32(0u, 42u, 0u, (unsigned int)b, kb0, kb1);  // batch key
    threefry2x32(kb0, kb1, 0u, 0u, ka0, ka1);              // carried key
    threefry2x32(kb0, kb1, 0u, 1u, u0, u1);                // round-1 subkey
    ws->subkeys[b][0] = u0; ws->subkeys[b][1] = u1;
    threefry2x32(ka0, ka1, 0u, 1u, u0, u1);                // round-2 subkey
    ws->subkeys[b][2] = u0; ws->subkeys[b][3] = u1;
  }
}

// ------------------- K1a (big path): compute bits1(store) + bits2(capture)
__global__ __launch_bounds__(256) void k1a_gen(WS* __restrict__ ws) {
  const int b = blockIdx.x >> 5, chunk = blockIdx.x & 31, t = threadIdx.x;
  const unsigned int s1k0 = ws->subkeys[b][0], s1k1 = ws->subkeys[b][1];
  const unsigned int s2k0 = ws->subkeys[b][2], s2k1 = ws->subkeys[b][3];
  const unsigned int i0 = (unsigned int)chunk * 8192u;
  for (int j = 0; j < 32; ++j) {
    const unsigned int i = i0 + (unsigned int)(j * 256 + t);
    ws->bits1[b][i] = rb32(s1k0, s1k1, i);
    const unsigned int bits2 = rb32(s2k0, s2k1, i);
    if (bits2 < THRESH2) {
      const unsigned int pos = atomicAdd(&ws->cnt2[b], 1u);
      if (pos < CAP2)
        ws->list2[b][pos] = ((unsigned long long)bits2 << 18) | (unsigned long long)i;
    }
  }
}

// ----------------------- K1b (big path): histogram from stored bits1 (mem-bound)
__global__ __launch_bounds__(256) void k1b_hist(WS* __restrict__ ws) {
  const int b = blockIdx.x >> 5, chunk = blockIdx.x & 31, t = threadIdx.x;
  __shared__ unsigned int lhist[NBIN];
  for (int i = t; i < NBIN; i += 256) lhist[i] = 0u;
  __syncthreads();
  const uint4* p = (const uint4*)&ws->bits1[b][(unsigned int)chunk * 8192u];
  for (int j = 0; j < 8; ++j) {
    const uint4 v = p[j * 256 + t];
    atomicAdd(&lhist[v.x >> 22], 1u);
    atomicAdd(&lhist[v.y >> 22], 1u);
    atomicAdd(&lhist[v.z >> 22], 1u);
    atomicAdd(&lhist[v.w >> 22], 1u);
  }
  __syncthreads();
  for (int i = t; i < NBIN; i += 256)
    if (lhist[i]) atomicAdd(&ws->hist[b][i], lhist[i]);
}

// ------------- K1 (fallback path, small ws): histogram + capture, one pass
__global__ __launch_bounds__(256) void k1_scan(WS* __restrict__ ws) {
  const int b = blockIdx.x >> 5, chunk = blockIdx.x & 31, t = threadIdx.x;
  __shared__ unsigned int lhist[NBIN];
  for (int i = t; i < NBIN; i += 256) lhist[i] = 0u;
  __syncthreads();
  const unsigned int s1k0 = ws->subkeys[b][0], s1k1 = ws->subkeys[b][1];
  const unsigned int s2k0 = ws->subkeys[b][2], s2k1 = ws->subkeys[b][3];
  const unsigned int i0 = (unsigned int)chunk * 8192u;
  for (int j = 0; j < 32; ++j) {
    const unsigned int i = i0 + (unsigned int)(j * 256 + t);
    const unsigned int bits1 = rb32(s1k0, s1k1, i);
    atomicAdd(&lhist[bits1 >> 22], 1u);
    const unsigned int bits2 = rb32(s2k0, s2k1, i);
    if (bits2 < THRESH2) {
      const unsigned int pos = atomicAdd(&ws->cnt2[b], 1u);
      if (pos < CAP2)
        ws->list2[b][pos] = ((unsigned long long)bits2 << 18) | (unsigned long long)i;
    }
  }
  __syncthreads();
  for (int i = t; i < NBIN; i += 256)
    if (lhist[i]) atomicAdd(&ws->hist[b][i], lhist[i]);
}

// -------------------------- K2: top-8 of round-2; map ranks -> (bin, residual)
__global__ __launch_bounds__(256) void k2_select(WS* __restrict__ ws) {
  const int b = blockIdx.x, t = threadIdx.x;
  const int lane = t & 63, wv = t >> 6;
  __shared__ unsigned long long lc[CAP2];
  __shared__ unsigned long long wmin[4];
  __shared__ unsigned int lbins[NBIN + 1];
  __shared__ unsigned int lq[NCLUST];
  __shared__ unsigned int psum[256];
  const unsigned int c2 = ws->cnt2[b];
  const int m2 = (int)(c2 < CAP2 ? c2 : CAP2);
  for (int e = t; e < m2; e += 256) lc[e] = ws->list2[b][e];
  __syncthreads();
  // extract the 8 smallest composites; low 18 bits give rank q into round-1 order
  for (int j = 0; j < NCLUST; ++j) {
    unsigned long long lm = ~0ull;
    for (int e = t; e < m2; e += 256) lm = umin64(lm, lc[e]);
#pragma unroll
    for (int off = 32; off > 0; off >>= 1)
      lm = umin64(lm, __shfl_down(lm, off, 64));
    if (lane == 0) wmin[wv] = lm;
    __syncthreads();
    if (t == 0) {
      const unsigned long long M =
          umin64(umin64(wmin[0], wmin[1]), umin64(wmin[2], wmin[3]));
      wmin[0] = M;
      lq[j] = (unsigned int)(M & IDXMASK);
    }
    __syncthreads();
    const unsigned long long M = wmin[0];
    for (int e = t; e < m2; e += 256)
      if (lc[e] == M) lc[e] = ~0ull;
    __syncthreads();
  }
  // parallel exclusive prefix over the 1024-bin histogram
  unsigned int h[4];
  unsigned int s = 0;
  {
    const int base = t * 4;
#pragma unroll
    for (int r = 0; r < 4; ++r) { h[r] = ws->hist[b][base + r]; s += h[r]; }
    psum[t] = s;
  }
  __syncthreads();
  for (int st = 1; st < 256; st <<= 1) {
    unsigned int v = 0;
    if (t >= st) v = psum[t - st];
    __syncthreads();
    psum[t] += v;
    __syncthreads();
  }
  {
    unsigned int run = psum[t] - s;  // exclusive offset of this thread's 4 bins
    const int base = t * 4;
#pragma unroll
    for (int r = 0; r < 4; ++r) { lbins[base + r] = run; run += h[r]; }
    if (t == 255) lbins[NBIN] = run;  // == NPIX
  }
  __syncthreads();
  {
    const int base = t * 4;
#pragma unroll
    for (int r = 0; r < 4; ++r) {
      const unsigned int lo = lbins[base + r], hi = lbins[base + r + 1];
      for (int j = 0; j < NCLUST; ++j) {
        const unsigned int q = lq[j];
        if (q >= lo && q < hi) {
          ws->binr[b][j][0] = (unsigned int)(base + r);
          ws->binr[b][j][1] = q - lo;
        }
      }
    }
  }
}

// ------------------ K3a (big path): capture bin candidates from stored bits1
__global__ __launch_bounds__(256) void k3a_read(WS* __restrict__ ws) {
  const int b = blockIdx.x >> 5, chunk = blockIdx.x & 31, t = threadIdx.x;
  unsigned int bins[NCLUST];
#pragma unroll
  for (int j = 0; j < NCLUST; ++j) bins[j] = ws->binr[b][j][0];
  const unsigned int i0 = (unsigned int)chunk * 8192u;
  const uint4* p = (const uint4*)&ws->bits1[b][i0];
  for (int jj = 0; jj < 8; ++jj) {
    const uint4 v = p[jj * 256 + t];
    const unsigned int iv[4] = {v.x, v.y, v.z, v.w};
#pragma unroll
    for (int c = 0; c < 4; ++c) {
      const unsigned int bits1 = iv[c];
      const unsigned int i = i0 + (unsigned int)((jj * 256 + t) * 4 + c);
      const unsigned int bin = bits1 >> 22;
      const unsigned long long comp =
          ((unsigned long long)bits1 << 18) | (unsigned long long)i;
#pragma unroll
      for (int j = 0; j < NCLUST; ++j) {
        if (bin == bins[j]) {
          const unsigned int pos = atomicAdd(&ws->cnt1[b][j], 1u);
          if (pos < CAP1) ws->list1[b][j][pos] = comp;
        }
      }
    }
  }
}

// ----------------- K3 (fallback): recompute bits1, capture bin candidates
__global__ __launch_bounds__(256) void k3_scan(WS* __restrict__ ws) {
  const int b = blockIdx.x >> 5, chunk = blockIdx.x & 31, t = threadIdx.x;
  const unsigned int s1k0 = ws->subkeys[b][0], s1k1 = ws->subkeys[b][1];
  unsigned int bins[NCLUST];
#pragma unroll
  for (int j = 0; j < NCLUST; ++j) bins[j] = ws->binr[b][j][0];
  const unsigned int i0 = (unsigned int)chunk * 8192u;
  for (int jj = 0; jj < 32; ++jj) {
    const unsigned int i = i0 + (unsigned int)(jj * 256 + t);
    const unsigned int bits1 = rb32(s1k0, s1k1, i);
    const unsigned int bin = bits1 >> 22;
    const unsigned long long comp =
        ((unsigned long long)bits1 << 18) | (unsigned long long)i;
#pragma unroll
    for (int j = 0; j < NCLUST; ++j) {
      if (bin == bins[j]) {
        const unsigned int pos = atomicAdd(&ws->cnt1[b][j], 1u);
        if (pos < CAP1) ws->list1[b][j][pos] = comp;
      }
    }
  }
}

// ------------------- K4: in-bin rank selection -> init centroid gather
__global__ __launch_bounds__(256) void k4_pick(const float* __restrict__ in,
                                               WS* __restrict__ ws) {
  const int b = blockIdx.x >> 3, j = blockIdx.x & 7, t = threadIdx.x;
  __shared__ unsigned long long l1[CAP1];
  const unsigned int c1 = ws->cnt1[b][j];
  const int m = (int)(c1 < CAP1 ? c1 : CAP1);
  const unsigned int r = ws->binr[b][j][1];
  for (int e = t; e < m; e += 256) l1[e] = ws->list1[b][j][e];
  __syncthreads();
  for (int e = t; e < m; e += 256) {
    const unsigned long long v = l1[e];
    unsigned int rank = 0;
    for (int f = 0; f < m; ++f) rank += (l1[f] < v) ? 1u : 0u;
    if (rank == r) {
      const unsigned int i = (unsigned int)(v & IDXMASK);
      const float* p = in + ((size_t)b * NPIX + i) * 3;
      ws->cent[0][b][j][0] = p[0];
      ws->cent[0][b][j][1] = p[1];
      ws->cent[0][b][j][2] = p[2];
    }
  }
}

// --------------- assign + accumulate + fused last-block centroid update
__global__ __launch_bounds__(256) void kmeans_assign(const float* __restrict__ in,
                                                     WS* __restrict__ ws,
                                                     float* __restrict__ out,
                                                     int iter) {
  const int b = blockIdx.x >> 4, chunk = blockIdx.x & 15, t = threadIdx.x;
  float ca[NCLUST], cb[NCLUST], cc[NCLUST], cd[NCLUST];
#pragma unroll
  for (int k = 0; k < NCLUST; ++k) {
    const float x = ws->cent[iter][b][k][0];
    const float y = ws->cent[iter][b][k][1];
    const float z = ws->cent[iter][b][k][2];
    ca[k] = -2.f * x; cb[k] = -2.f * y; cc[k] = -2.f * z;
    // +8 bias keeps t_k > 0 so fp32 bit pattern is order-preserving as u32
    cd[k] = fmaf(x, x, fmaf(y, y, z * z)) + 8.f;
  }
  float ax[NCLUST], ay[NCLUST], az[NCLUST], an[NCLUST];
#pragma unroll
  for (int k = 0; k < NCLUST; ++k) { ax[k] = 0.f; ay[k] = 0.f; az[k] = 0.f; an[k] = 0.f; }

  const float4* in4 = (const float4*)(in + (size_t)b * NPIX * 3);
  const int f4base = chunk * 12288;
  for (int jj = 0; jj < 16; ++jj) {
    const int g = jj * 256 + t;
    const int fb = f4base + g * 3;
    const float4 v0 = in4[fb], v1 = in4[fb + 1], v2 = in4[fb + 2];
    float px[4], py[4], pz[4];
    px[0] = v0.x; py[0] = v0.y; pz[0] = v0.z;
    px[1] = v0.w; py[1] = v1.x; pz[1] = v1.y;
    px[2] = v1.z; py[2] = v1.w; pz[2] = v2.x;
    px[3] = v2.y; py[3] = v2.z; pz[3] = v2.w;
#pragma unroll
    for (int p = 0; p < 4; ++p) {
      const float x = px[p], y = py[p], z = pz[p];
      unsigned int best = 0xFFFFFFFFu;
#pragma unroll
      for (int k = 0; k < NCLUST; ++k) {
        const float tk = fmaf(ca[k], x, fmaf(cb[k], y, fmaf(cc[k], z, cd[k])));
        // (bits & ~7) | k : 3-bit index packed in LSBs, first-min tie-break
        const unsigned int key = (__float_as_uint(tk) & ~7u) | (unsigned int)k;
        best = best < key ? best : key;
      }
      const int bk = (int)(best & 7u);
#pragma unroll
      for (int k = 0; k < NCLUST; ++k) {
        const float w = (bk == k) ? 1.f : 0.f;
        ax[k] = fmaf(w, x, ax[k]);
        ay[k] = fmaf(w, y, ay[k]);
        az[k] = fmaf(w, z, az[k]);
        an[k] += w;
      }
    }
  }
  const int lane = t & 63;
#pragma unroll
  for (int k = 0; k < NCLUST; ++k) {
    float vx = ax[k], vy = ay[k], vz = az[k], vn = an[k];
#pragma unroll
    for (int off = 32; off > 0; off >>= 1) {
      vx += __shfl_down(vx, off, 64);
      vy += __shfl_down(vy, off, 64);
      vz += __shfl_down(vz, off, 64);
      vn += __shfl_down(vn, off, 64);
    }
    if (lane == 0) {
      atomicAdd(&ws->sums[iter][b][k][0], vx);
      atomicAdd(&ws->sums[iter][b][k][1], vy);
      atomicAdd(&ws->sums[iter][b][k][2], vz);
      atomicAdd(&ws->sums[iter][b][k][3], vn);
    }
  }
  if (lane == 0) __threadfence();   // order this wave's atomics before ticket
  __syncthreads();
  __shared__ unsigned int last;
  if (t == 0) {
    const unsigned int old = atomicAdd(&ws->done[iter][b], 1u);
    last = (old == 15u) ? 1u : 0u;
  }
  __syncthreads();
  if (last && t < NCLUST) {        // winner block: fused centroid update
    const int k = t;
    const float sx = atomicAdd(&ws->sums[iter][b][k][0], 0.f);  // coherent reads
    const float sy = atomicAdd(&ws->sums[iter][b][k][1], 0.f);
    const float sz = atomicAdd(&ws->sums[iter][b][k][2], 0.f);
    const float cnt = atomicAdd(&ws->sums[iter][b][k][3], 0.f);
    const float denom = fmaxf(cnt, 1.f);
    const float ox = ws->cent[iter][b][k][0];
    const float oy = ws->cent[iter][b][k][1];
    const float oz = ws->cent[iter][b][k][2];
    const float nx = (cnt > 0.f) ? sx / denom : ox;
    const float ny = (cnt > 0.f) ? sy / denom : oy;
    const float nz = (cnt > 0.f) ? sz / denom : oz;
    ws->cent[iter + 1][b][k][0] = nx;
    ws->cent[iter + 1][b][k][1] = ny;
    ws->cent[iter + 1][b][k][2] = nz;
    if (iter == NITER - 1) {
      const int o = (b * NCLUST + k) * 3;
      out[o + 0] = nx; out[o + 1] = ny; out[o + 2] = nz;
    }
  }
}

extern "C" void kernel_launch(void* const* d_in, const int* in_sizes, int n_in,
                              void* d_out, int out_size, void* d_ws, size_t ws_size,
                              hipStream_t stream) {
  const float* in = (const float*)d_in[0];
  float* out = (float*)d_out;
  WS* ws = (WS*)d_ws;
  const bool big = ws_size >= sizeof(WS);   // deterministic per-launch: graph-safe

  k0_setup<<<NBATCH, 256, 0, stream>>>(in, ws);
  if (big) {
    k1a_gen<<<NBATCH * 32, 256, 0, stream>>>(ws);
    k1b_hist<<<NBATCH * 32, 256, 0, stream>>>(ws);
  } else {
    k1_scan<<<NBATCH * 32, 256, 0, stream>>>(ws);
  }
  k2_select<<<NBATCH, 256, 0, stream>>>(ws);
  if (big) {
    k3a_read<<<NBATCH * 32, 256, 0, stream>>>(ws);
  } else {
    k3_scan<<<NBATCH * 32, 256, 0, stream>>>(ws);
  }
  k4_pick<<<NBATCH * NCLUST, 256, 0, stream>>>(in, ws);
  for (int it = 0; it < NITER; ++it)
    kmeans_assign<<<NBATCH * 16, 256, 0, stream>>>(in, ws, out, it);
}

// Round 4
// 935.635 us; speedup vs baseline: 2.4740x; 2.4740x over previous
//
#include <hip/hip_runtime.h>

// K-means (8 clusters, 10 iters) on 64 batches of 512*512 RGB pixels,
// bit-exact jax.random init (partitionable threefry, xor-fold bits,
// 2-round stable-sort permutation). Correctness locked since round 2.
//
// Round-4 (perf):
//  - REVERTED round-3 fused update w/ __threadfence (L2-writeback per block
//    thrashed per-XCD L2: +900 us). No atomics/fences in the iteration loop:
//    each assign block writes a private partial-sum slot; the NEXT dispatch
//    redundantly reduces partials + computes centroids in-block (phase A).
//    Dispatch boundaries provide visibility for free.
//  - k1: single pass computes threefry bits1 (stores 64 MB) + bits2 capture +
//    LDS histogram from registers. k3a reads stored bits1 (memory-bound).
//  - #pragma unroll 1 on threefry loop (icache-thrash theory for the
//    38%-VALUBusy/197us mystery), unroll 4 on assign pixel loop.

#define NBATCH 64
#define NPIX   262144   // 512*512 = 2^18
#define NCLUST 8
#define NITER  10
#define NBIN   1024
#define CAP2   1024     // round-2 candidates: E=512, +22 sigma
#define CAP1   512      // per-bin round-1 candidates: E=256, +16 sigma
#define THRESH2 (1u << 23)
#define IDXMASK 0x3FFFFull
#define NCHUNK 16       // assign blocks per batch

struct WS {
  unsigned long long list2[NBATCH][CAP2];            // (bits2<<18)|pos
  unsigned long long list1[NBATCH][NCLUST][CAP1];    // (bits1<<18)|i
  unsigned int subkeys[NBATCH][4];
  unsigned int hist[NBATCH][NBIN];
  unsigned int cnt2[NBATCH];
  unsigned int cnt1[NBATCH][NCLUST];
  unsigned int binr[NBATCH][NCLUST][2];              // bin, intra-bin rank
  float cent[NITER][NBATCH][NCLUST][3];              // C_iter per iteration
  float partial[2][NBATCH][NCHUNK][NCLUST][4];       // double-buffered partials
  unsigned int bits1[NBATCH][NPIX];                  // 64 MB stored stream
};

__device__ __forceinline__ unsigned int rotl32(unsigned int x, int d) {
  return __builtin_amdgcn_alignbit(x, x, (unsigned int)(32 - d));
}

__device__ __forceinline__ void threefry2x32(unsigned int k0, unsigned int k1,
                                             unsigned int x0, unsigned int x1,
                                             unsigned int &y0, unsigned int &y1) {
  const unsigned int ks2 = k0 ^ k1 ^ 0x1BD11BDAu;
  x0 += k0; x1 += k1;
#define TF_ROUND(r) { x0 += x1; x1 = rotl32(x1, r); x1 ^= x0; }
  TF_ROUND(13) TF_ROUND(15) TF_ROUND(26) TF_ROUND(6)
  x0 += k1;  x1 += ks2 + 1u;
  TF_ROUND(17) TF_ROUND(29) TF_ROUND(16) TF_ROUND(24)
  x0 += ks2; x1 += k0 + 2u;
  TF_ROUND(13) TF_ROUND(15) TF_ROUND(26) TF_ROUND(6)
  x0 += k0;  x1 += k1 + 3u;
  TF_ROUND(17) TF_ROUND(29) TF_ROUND(16) TF_ROUND(24)
  x0 += k1;  x1 += ks2 + 4u;
  TF_ROUND(13) TF_ROUND(15) TF_ROUND(26) TF_ROUND(6)
  x0 += ks2; x1 += k0 + 5u;
#undef TF_ROUND
  y0 = x0; y1 = x1;
}

__device__ __forceinline__ unsigned int rb32(unsigned int k0, unsigned int k1,
                                             unsigned int i) {
  unsigned int y0, y1;
  threefry2x32(k0, k1, 0u, i, y0, y1);
  return y0 ^ y1;
}

__device__ __forceinline__ unsigned long long umin64(unsigned long long a,
                                                     unsigned long long b) {
  return a < b ? a : b;
}

// ---------------------------------------------------------------- K0: setup
__global__ __launch_bounds__(256) void k0_setup(const float* __restrict__ in,
                                                WS* __restrict__ ws) {
  const int b = blockIdx.x, t = threadIdx.x;
  for (int i = t; i < NBIN; i += 256) ws->hist[b][i] = 0u;
  if (t < NCLUST) {
    ws->cnt1[b][t] = 0u;
    const float* p = in + ((size_t)b * NPIX + (size_t)t) * 3;  // fallback init
    ws->cent[0][b][t][0] = p[0];
    ws->cent[0][b][t][1] = p[1];
    ws->cent[0][b][t][2] = p[2];
  }
  if (t == 0) {
    ws->cnt2[b] = 0u;
    unsigned int kb0, kb1, ka0, ka1, u0, u1;
    threefry2x32(0u, 42u, 0u, (unsigned int)b, kb0, kb1);  // batch key
    threefry2x32(kb0, kb1, 0u, 0u, ka0, ka1);              // carried key
    threefry2x32(kb0, kb1, 0u, 1u, u0, u1);                // round-1 subkey
    ws->subkeys[b][0] = u0; ws->subkeys[b][1] = u1;
    threefry2x32(ka0, ka1, 0u, 1u, u0, u1);                // round-2 subkey
    ws->subkeys[b][2] = u0; ws->subkeys[b][3] = u1;
  }
}

// ------- K1: threefry both streams; store bits1, LDS-hist, capture bits2
__global__ __launch_bounds__(256) void k1_scan(WS* __restrict__ ws) {
  const int b = blockIdx.x >> 5, chunk = blockIdx.x & 31, t = threadIdx.x;
  __shared__ unsigned int lhist[NBIN];
  for (int i = t; i < NBIN; i += 256) lhist[i] = 0u;
  __syncthreads();
  const unsigned int s1k0 = ws->subkeys[b][0], s1k1 = ws->subkeys[b][1];
  const unsigned int s2k0 = ws->subkeys[b][2], s2k1 = ws->subkeys[b][3];
  const unsigned int i0 = (unsigned int)chunk * 8192u + (unsigned int)t;
  unsigned int* __restrict__ bout = &ws->bits1[b][0];
#pragma unroll 1
  for (int j = 0; j < 32; ++j) {
    const unsigned int i = i0 + (unsigned int)(j * 256);
    const unsigned int bits1 = rb32(s1k0, s1k1, i);
    bout[i] = bits1;
    atomicAdd(&lhist[bits1 >> 22], 1u);
    const unsigned int bits2 = rb32(s2k0, s2k1, i);
    if (bits2 < THRESH2) {
      const unsigned int pos = atomicAdd(&ws->cnt2[b], 1u);
      if (pos < CAP2)
        ws->list2[b][pos] = ((unsigned long long)bits2 << 18) | (unsigned long long)i;
    }
  }
  __syncthreads();
  for (int i = t; i < NBIN; i += 256)
    if (lhist[i]) atomicAdd(&ws->hist[b][i], lhist[i]);
}

// -------------------------- K2: top-8 of round-2; map ranks -> (bin, residual)
__global__ __launch_bounds__(256) void k2_select(WS* __restrict__ ws) {
  const int b = blockIdx.x, t = threadIdx.x;
  const int lane = t & 63, wv = t >> 6;
  __shared__ unsigned long long lc[CAP2];
  __shared__ unsigned long long wmin[4];
  __shared__ unsigned int lbins[NBIN + 1];
  __shared__ unsigned int lq[NCLUST];
  __shared__ unsigned int psum[256];
  const unsigned int c2 = ws->cnt2[b];
  const int m2 = (int)(c2 < CAP2 ? c2 : CAP2);
  for (int e = t; e < m2; e += 256) lc[e] = ws->list2[b][e];
  __syncthreads();
  for (int j = 0; j < NCLUST; ++j) {
    unsigned long long lm = ~0ull;
    for (int e = t; e < m2; e += 256) lm = umin64(lm, lc[e]);
#pragma unroll
    for (int off = 32; off > 0; off >>= 1)
      lm = umin64(lm, __shfl_down(lm, off, 64));
    if (lane == 0) wmin[wv] = lm;
    __syncthreads();
    if (t == 0) {
      const unsigned long long M =
          umin64(umin64(wmin[0], wmin[1]), umin64(wmin[2], wmin[3]));
      wmin[0] = M;
      lq[j] = (unsigned int)(M & IDXMASK);
    }
    __syncthreads();
    const unsigned long long M = wmin[0];
    for (int e = t; e < m2; e += 256)
      if (lc[e] == M) lc[e] = ~0ull;
    __syncthreads();
  }
  unsigned int h[4];
  unsigned int s = 0;
  {
    const int base = t * 4;
#pragma unroll
    for (int r = 0; r < 4; ++r) { h[r] = ws->hist[b][base + r]; s += h[r]; }
    psum[t] = s;
  }
  __syncthreads();
  for (int st = 1; st < 256; st <<= 1) {
    unsigned int v = 0;
    if (t >= st) v = psum[t - st];
    __syncthreads();
    psum[t] += v;
    __syncthreads();
  }
  {
    unsigned int run = psum[t] - s;
    const int base = t * 4;
#pragma unroll
    for (int r = 0; r < 4; ++r) { lbins[base + r] = run; run += h[r]; }
    if (t == 255) lbins[NBIN] = run;  // == NPIX
  }
  __syncthreads();
  {
    const int base = t * 4;
#pragma unroll
    for (int r = 0; r < 4; ++r) {
      const unsigned int lo = lbins[base + r], hi = lbins[base + r + 1];
      for (int j = 0; j < NCLUST; ++j) {
        const unsigned int q = lq[j];
        if (q >= lo && q < hi) {
          ws->binr[b][j][0] = (unsigned int)(base + r);
          ws->binr[b][j][1] = q - lo;
        }
      }
    }
  }
}

// ------------------ K3a: capture bin candidates from stored bits1 (mem-bound)
__global__ __launch_bounds__(256) void k3a_read(WS* __restrict__ ws) {
  const int b = blockIdx.x >> 5, chunk = blockIdx.x & 31, t = threadIdx.x;
  unsigned int bins[NCLUST];
#pragma unroll
  for (int j = 0; j < NCLUST; ++j) bins[j] = ws->binr[b][j][0];
  const unsigned int i0 = (unsigned int)chunk * 8192u;
  const uint4* __restrict__ p = (const uint4*)&ws->bits1[b][i0];
#pragma unroll 1
  for (int jj = 0; jj < 8; ++jj) {
    const uint4 v = p[jj * 256 + t];
    const unsigned int iv[4] = {v.x, v.y, v.z, v.w};
#pragma unroll
    for (int c = 0; c < 4; ++c) {
      const unsigned int bits1 = iv[c];
      const unsigned int i = i0 + (unsigned int)((jj * 256 + t) * 4 + c);
      const unsigned int bin = bits1 >> 22;
      const unsigned long long comp =
          ((unsigned long long)bits1 << 18) | (unsigned long long)i;
#pragma unroll
      for (int j = 0; j < NCLUST; ++j) {
        if (bin == bins[j]) {
          const unsigned int pos = atomicAdd(&ws->cnt1[b][j], 1u);
          if (pos < CAP1) ws->list1[b][j][pos] = comp;
        }
      }
    }
  }
}

// ------------------- K4: in-bin rank selection -> init centroid gather
__global__ __launch_bounds__(256) void k4_pick(const float* __restrict__ in,
                                               WS* __restrict__ ws) {
  const int b = blockIdx.x >> 3, j = blockIdx.x & 7, t = threadIdx.x;
  __shared__ unsigned long long l1[CAP1];
  const unsigned int c1 = ws->cnt1[b][j];
  const int m = (int)(c1 < CAP1 ? c1 : CAP1);
  const unsigned int r = ws->binr[b][j][1];
  for (int e = t; e < m; e += 256) l1[e] = ws->list1[b][j][e];
  __syncthreads();
  for (int e = t; e < m; e += 256) {
    const unsigned long long v = l1[e];
    unsigned int rank = 0;
    for (int f = 0; f < m; ++f) rank += (l1[f] < v) ? 1u : 0u;
    if (rank == r) {
      const unsigned int i = (unsigned int)(v & IDXMASK);
      const float* p = in + ((size_t)b * NPIX + i) * 3;
      ws->cent[0][b][j][0] = p[0];
      ws->cent[0][b][j][1] = p[1];
      ws->cent[0][b][j][2] = p[2];
    }
  }
}

// ------- assign: phase A recompute centroids from prev partials (redundant
//         per block, fence-free), phase B assign+accumulate into private slot
__global__ __launch_bounds__(256) void kmeans_assign(const float* __restrict__ in,
                                                     WS* __restrict__ ws,
                                                     int iter) {
  const int b = blockIdx.x >> 4, chunk = blockIdx.x & 15, t = threadIdx.x;
  __shared__ float scent[NCLUST][3];
  __shared__ float sred[4][NCLUST][4];

  // ---- phase A: centroids for this iteration
  if (iter == 0) {
    if (t < NCLUST * 3) (&scent[0][0])[t] = (&ws->cent[0][b][0][0])[t];
  } else {
    const int pb = (iter - 1) & 1;
    if (t < 32) {
      const int k = t >> 2, c = t & 3;
      float s = 0.f;
#pragma unroll
      for (int ch = 0; ch < NCHUNK; ++ch) s += ws->partial[pb][b][ch][k][c];
      sred[0][k][c] = s;
    }
    __syncthreads();
    if (t < NCLUST) {
      const int k = t;
      const float cnt = sred[0][k][3];
      const float denom = fmaxf(cnt, 1.f);
      float nx, ny, nz;
      if (cnt > 0.f) {
        nx = sred[0][k][0] / denom;
        ny = sred[0][k][1] / denom;
        nz = sred[0][k][2] / denom;
      } else {
        nx = ws->cent[iter - 1][b][k][0];
        ny = ws->cent[iter - 1][b][k][1];
        nz = ws->cent[iter - 1][b][k][2];
      }
      scent[k][0] = nx; scent[k][1] = ny; scent[k][2] = nz;
      // redundant identical writes from all 16 blocks of batch b: benign;
      // read only by the NEXT dispatch (fallback path).
      ws->cent[iter][b][k][0] = nx;
      ws->cent[iter][b][k][1] = ny;
      ws->cent[iter][b][k][2] = nz;
    }
  }
  __syncthreads();

  float ca[NCLUST], cb[NCLUST], cc[NCLUST], cd[NCLUST];
#pragma unroll
  for (int k = 0; k < NCLUST; ++k) {
    const float x = scent[k][0], y = scent[k][1], z = scent[k][2];
    ca[k] = -2.f * x; cb[k] = -2.f * y; cc[k] = -2.f * z;
    // +8 bias keeps t_k > 0 so the fp32 bit pattern is order-preserving as u32
    cd[k] = fmaf(x, x, fmaf(y, y, z * z)) + 8.f;
  }
  float ax[NCLUST], ay[NCLUST], az[NCLUST], an[NCLUST];
#pragma unroll
  for (int k = 0; k < NCLUST; ++k) { ax[k] = 0.f; ay[k] = 0.f; az[k] = 0.f; an[k] = 0.f; }

  // ---- phase B: 16384 pixels per block
  const float4* __restrict__ in4 = (const float4*)(in + (size_t)b * NPIX * 3);
  const int f4base = chunk * 12288;
#pragma unroll 4
  for (int jj = 0; jj < 16; ++jj) {
    const int g = jj * 256 + t;
    const int fb = f4base + g * 3;
    const float4 v0 = in4[fb], v1 = in4[fb + 1], v2 = in4[fb + 2];
    float px[4], py[4], pz[4];
    px[0] = v0.x; py[0] = v0.y; pz[0] = v0.z;
    px[1] = v0.w; py[1] = v1.x; pz[1] = v1.y;
    px[2] = v1.z; py[2] = v1.w; pz[2] = v2.x;
    px[3] = v2.y; py[3] = v2.z; pz[3] = v2.w;
#pragma unroll
    for (int p = 0; p < 4; ++p) {
      const float x = px[p], y = py[p], z = pz[p];
      unsigned int best = 0xFFFFFFFFu;
#pragma unroll
      for (int k = 0; k < NCLUST; ++k) {
        const float tk = fmaf(ca[k], x, fmaf(cb[k], y, fmaf(cc[k], z, cd[k])));
        const unsigned int key = (__float_as_uint(tk) & ~7u) | (unsigned int)k;
        best = best < key ? best : key;
      }
      const int bk = (int)(best & 7u);
#pragma unroll
      for (int k = 0; k < NCLUST; ++k) {
        const float w = (bk == k) ? 1.f : 0.f;
        ax[k] = fmaf(w, x, ax[k]);
        ay[k] = fmaf(w, y, ay[k]);
        az[k] = fmaf(w, z, az[k]);
        an[k] += w;
      }
    }
  }

  // ---- block-level reduction into private partial slot (no atomics)
  const int lane = t & 63, wv = t >> 6;
#pragma unroll
  for (int k = 0; k < NCLUST; ++k) {
    float vx = ax[k], vy = ay[k], vz = az[k], vn = an[k];
#pragma unroll
    for (int off = 32; off > 0; off >>= 1) {
      vx += __shfl_down(vx, off, 64);
      vy += __shfl_down(vy, off, 64);
      vz += __shfl_down(vz, off, 64);
      vn += __shfl_down(vn, off, 64);
    }
    if (lane == 0) {
      sred[wv][k][0] = vx; sred[wv][k][1] = vy;
      sred[wv][k][2] = vz; sred[wv][k][3] = vn;
    }
  }
  __syncthreads();
  if (t < 32) {
    const int k = t >> 2, c = t & 3;
    const float p = sred[0][k][c] + sred[1][k][c] + sred[2][k][c] + sred[3][k][c];
    ws->partial[iter & 1][b][chunk][k][c] = p;
  }
}

// ----------------------- final: C_10 from iter-9 partials -> output
__global__ __launch_bounds__(64) void kfinal(WS* __restrict__ ws,
                                             float* __restrict__ out) {
  const int b = blockIdx.x, t = threadIdx.x;
  __shared__ float s[NCLUST][4];
  if (t < 32) {
    const int k = t >> 2, c = t & 3;
    float v = 0.f;
#pragma unroll
    for (int ch = 0; ch < NCHUNK; ++ch)
      v += ws->partial[(NITER - 1) & 1][b][ch][k][c];
    s[k][c] = v;
  }
  __syncthreads();
  if (t < NCLUST) {
    const int k = t;
    const float cnt = s[k][3];
    const float denom = fmaxf(cnt, 1.f);
    float nx, ny, nz;
    if (cnt > 0.f) {
      nx = s[k][0] / denom; ny = s[k][1] / denom; nz = s[k][2] / denom;
    } else {
      nx = ws->cent[NITER - 1][b][k][0];
      ny = ws->cent[NITER - 1][b][k][1];
      nz = ws->cent[NITER - 1][b][k][2];
    }
    const int o = (b * NCLUST + k) * 3;
    out[o + 0] = nx; out[o + 1] = ny; out[o + 2] = nz;
  }
}

extern "C" void kernel_launch(void* const* d_in, const int* in_sizes, int n_in,
                              void* d_out, int out_size, void* d_ws, size_t ws_size,
                              hipStream_t stream) {
  const float* in = (const float*)d_in[0];
  float* out = (float*)d_out;
  WS* ws = (WS*)d_ws;   // ~67 MB scratch

  k0_setup<<<NBATCH, 256, 0, stream>>>(in, ws);
  k1_scan<<<NBATCH * 32, 256, 0, stream>>>(ws);
  k2_select<<<NBATCH, 256, 0, stream>>>(ws);
  k3a_read<<<NBATCH * 32, 256, 0, stream>>>(ws);
  k4_pick<<<NBATCH * NCLUST, 256, 0, stream>>>(in, ws);
  for (int it = 0; it < NITER; ++it)
    kmeans_assign<<<NBATCH * NCHUNK, 256, 0, stream>>>(in, ws, it);
  kfinal<<<NBATCH, 64, 0, stream>>>(ws, out);
}